// Round 1
// baseline (693.122 us; speedup 1.0000x reference)
//
#include <hip/hip_runtime.h>
#include <hip/hip_bf16.h>

// SoftMoE: B=4, M=1024, D=768, E=16, P=64, F=3072, EP=1024, rows=B*M=4096
// d_out (fp32): outputs[4,1024,768] | probs[4,1024,16] | tops[4,1024,1] | hidden[4,16,64,3072]

typedef unsigned short u16;
typedef __bf16 bf16x8 __attribute__((ext_vector_type(8)));
typedef float f32x4 __attribute__((ext_vector_type(4)));

__device__ __forceinline__ float gelu_f(float x) {
    const float c = 0.7978845608028654f;  // sqrt(2/pi)
    float u = c * (x + 0.044715f * x * x * x);
    return 0.5f * x * (1.0f + tanhf(u));
}

__device__ __forceinline__ u16 f2b(float x) {
    union { float f; unsigned u; } v; v.f = x;
    unsigned r = v.u + 0x7FFF + ((v.u >> 16) & 1);
    return (u16)(r >> 16);
}

// ---------------------------------------------------------------------------
// fp32 GEMM (round-1, proven). Used for K1 always; K3-K6 on the fallback path.
// addr = z*aZ + (row>>6)*rgs + (row&63)*ld + k
template<bool TRANSA, bool DOGELU>
__global__ __launch_bounds__(256)
void gemm_k(const float* __restrict__ A, const float* __restrict__ Bm,
            const float* __restrict__ bias, float* __restrict__ C,
            int K, int lda, int ldb, int ldc,
            long aZ, long bZ, long cZ, int biasZ,
            long rgsA, long rgsC)
{
    __shared__ float As[16][128];
    __shared__ float Bs[16][64];
    const int z = blockIdx.z;
    A  += (long)z * aZ;
    Bm += (long)z * bZ;
    if (bias) bias += (long)z * biasZ;
    const int row0 = blockIdx.y * 128;
    const int col0 = blockIdx.x * 64;
    const int t  = threadIdx.x;
    const int tx = t & 15;
    const int ty = t >> 4;

    float acc[8][4];
    #pragma unroll
    for (int i = 0; i < 8; ++i)
        #pragma unroll
        for (int j = 0; j < 4; ++j) acc[i][j] = 0.f;

    for (int k0 = 0; k0 < K; k0 += 16) {
        if (TRANSA) {
            const int kk = t >> 5;
            const int ii = (t & 31) * 4;
            const float* pa = A + (long)(k0 + kk) * lda + (row0 + ii);
            float4 v0 = *(const float4*)pa;
            float4 v1 = *(const float4*)(pa + 8L * lda);
            *(float4*)&As[kk][ii]     = v0;
            *(float4*)&As[kk + 8][ii] = v1;
        } else {
            const int ii = t >> 1;
            const int kk = (t & 1) * 8;
            const int grow = row0 + ii;
            const float* pa = A + (long)(grow >> 6) * rgsA
                                + (long)(grow & 63) * lda + (k0 + kk);
            float4 v0 = *(const float4*)pa;
            float4 v1 = *(const float4*)(pa + 4);
            As[kk+0][ii] = v0.x; As[kk+1][ii] = v0.y;
            As[kk+2][ii] = v0.z; As[kk+3][ii] = v0.w;
            As[kk+4][ii] = v1.x; As[kk+5][ii] = v1.y;
            As[kk+6][ii] = v1.z; As[kk+7][ii] = v1.w;
        }
        {
            const int kk = t >> 4;
            const int jj = (t & 15) * 4;
            float4 v = *(const float4*)(Bm + (long)(k0 + kk) * ldb + (col0 + jj));
            *(float4*)&Bs[kk][jj] = v;
        }
        __syncthreads();
        #pragma unroll
        for (int k = 0; k < 16; ++k) {
            float a[8], b[4];
            *(float4*)&a[0] = *(const float4*)&As[k][ty * 8];
            *(float4*)&a[4] = *(const float4*)&As[k][ty * 8 + 4];
            *(float4*)&b[0] = *(const float4*)&Bs[k][tx * 4];
            #pragma unroll
            for (int i = 0; i < 8; ++i)
                #pragma unroll
                for (int j = 0; j < 4; ++j)
                    acc[i][j] = fmaf(a[i], b[j], acc[i][j]);
        }
        __syncthreads();
    }

    float bj[4] = {0.f, 0.f, 0.f, 0.f};
    if (bias) {
        #pragma unroll
        for (int j = 0; j < 4; ++j) bj[j] = bias[col0 + tx * 4 + j];
    }
    #pragma unroll
    for (int i = 0; i < 8; ++i) {
        const int grow = row0 + ty * 8 + i;
        const long rb = (long)(grow >> 6) * rgsC
                      + (long)(grow & 63) * ldc + (col0 + tx * 4);
        float rv[4];
        #pragma unroll
        for (int j = 0; j < 4; ++j) {
            float v = acc[i][j] + bj[j];
            if (DOGELU) v = gelu_f(v);
            rv[j] = v;
        }
        *(float4*)(C + (long)z * cZ + rb) = make_float4(rv[0], rv[1], rv[2], rv[3]);
    }
}

// ---------------------------------------------------------------------------
// bf16 MFMA GEMM. 128x128 tile, BK=64, 256 thr = 4 waves (2x2), 64x64/wave as
// 4x4 of v_mfma_f32_16x16x32_bf16. LDS [dim][64] bf16 with XOR chunk swizzle
// (chunk ^= row&7) -> conflict-free b128 staging writes AND fragment reads.
// A: bf16 or fp32 (converted in staging), grouped rows. B: bf16 [n][k].
template<bool AF32, bool DOGELU, bool CF32>
__global__ __launch_bounds__(256)
void mfma_gemm(const void* __restrict__ Av, const u16* __restrict__ Bt,
               const float* __restrict__ bias, void* __restrict__ Cv,
               int K, int lda, int ldb, int ldc,
               long aZ, long bZ, long cZ, int biasZ,
               long rgsA, long rgsC)
{
    __shared__ u16 As[128][64];
    __shared__ u16 Bs[128][64];
    const int z    = blockIdx.z;
    const int row0 = blockIdx.y * 128;
    const int col0 = blockIdx.x * 128;
    const int t    = threadIdx.x;
    const int lane = t & 63;
    const int wave = t >> 6;
    const int wr   = (wave >> 1) * 64;
    const int wc   = (wave & 1) * 64;

    const int srow  = t >> 1;   // staging row 0..127
    const int shalf = t & 1;    // which 32-elem k half
    const int agrow = row0 + srow;
    const long aRowOff = (long)z * aZ + (long)(agrow >> 6) * rgsA
                       + (long)(agrow & 63) * lda;
    const long bRowOff = (long)z * bZ + (long)(col0 + srow) * ldb;

    f32x4 acc[4][4] = {};

    for (int k0 = 0; k0 < K; k0 += 64) {
        // --- stage A ---
        if (AF32) {
            const float* pa = (const float*)Av + aRowOff + k0 + shalf * 32;
            #pragma unroll
            for (int q = 0; q < 4; ++q) {
                float4 u0 = *(const float4*)(pa + q * 8);
                float4 u1 = *(const float4*)(pa + q * 8 + 4);
                u16 tmp[8] = { f2b(u0.x), f2b(u0.y), f2b(u0.z), f2b(u0.w),
                               f2b(u1.x), f2b(u1.y), f2b(u1.z), f2b(u1.w) };
                const int cs = (shalf * 4 + q) ^ (srow & 7);
                *(uint4*)&As[srow][cs * 8] = *(const uint4*)tmp;
            }
        } else {
            const u16* pa = (const u16*)Av + aRowOff + k0 + shalf * 32;
            #pragma unroll
            for (int q = 0; q < 4; ++q) {
                uint4 v = *(const uint4*)(pa + q * 8);
                const int cs = (shalf * 4 + q) ^ (srow & 7);
                *(uint4*)&As[srow][cs * 8] = v;
            }
        }
        // --- stage B (always bf16 [n][k]) ---
        {
            const u16* pb = Bt + bRowOff + k0 + shalf * 32;
            #pragma unroll
            for (int q = 0; q < 4; ++q) {
                uint4 v = *(const uint4*)(pb + q * 8);
                const int cs = (shalf * 4 + q) ^ (srow & 7);
                *(uint4*)&Bs[srow][cs * 8] = v;
            }
        }
        __syncthreads();

        #pragma unroll
        for (int kk = 0; kk < 2; ++kk) {
            const int cchunk = kk * 4 + (lane >> 4);   // k chunk 0..7
            bf16x8 af[4], bfr[4];
            #pragma unroll
            for (int i = 0; i < 4; ++i) {
                const int m = wr + i * 16 + (lane & 15);
                af[i]  = __builtin_bit_cast(bf16x8,
                           *(const uint4*)&As[m][(cchunk ^ (m & 7)) * 8]);
                const int n = wc + i * 16 + (lane & 15);
                bfr[i] = __builtin_bit_cast(bf16x8,
                           *(const uint4*)&Bs[n][(cchunk ^ (n & 7)) * 8]);
            }
            #pragma unroll
            for (int i = 0; i < 4; ++i)
                #pragma unroll
                for (int j = 0; j < 4; ++j)
                    acc[i][j] = __builtin_amdgcn_mfma_f32_16x16x32_bf16(
                                    af[i], bfr[j], acc[i][j], 0, 0, 0);
        }
        __syncthreads();
    }

    // --- epilogue: C/D layout col=lane&15, row=(lane>>4)*4+reg ---
    const int cq = lane >> 4;
    #pragma unroll
    for (int j = 0; j < 4; ++j) {
        const int gcol = col0 + wc + j * 16 + (lane & 15);
        const float bv = bias ? bias[(long)z * biasZ + gcol] : 0.f;
        #pragma unroll
        for (int i = 0; i < 4; ++i) {
            #pragma unroll
            for (int r = 0; r < 4; ++r) {
                const int grow = row0 + wr + i * 16 + cq * 4 + r;
                const long co = (long)z * cZ + (long)(grow >> 6) * rgsC
                              + (long)(grow & 63) * ldc + gcol;
                float v = acc[i][j][r] + bv;
                if (DOGELU) v = gelu_f(v);
                if (CF32) ((float*)Cv)[co] = v;
                else      ((u16*)Cv)[co]  = f2b(v);
            }
        }
    }
}

// ---------------------------------------------------------------------------
// Transpose [z][R][C] (fp32 or bf16) -> [z][C][R] bf16. 64x64 tiles, 256 thr.
template<bool F32>
__global__ __launch_bounds__(256)
void transpose_k(const void* __restrict__ inV, u16* __restrict__ out, int R, int C)
{
    __shared__ u16 tile[64][72];
    const long zin = (long)blockIdx.z * R * C;
    const int r0 = blockIdx.y * 64, c0 = blockIdx.x * 64;
    const int t  = threadIdx.x;
    const int tr = t >> 4;
    const int tc = (t & 15) * 4;
    #pragma unroll
    for (int p = 0; p < 4; ++p) {
        const int r = tr + p * 16;
        if (F32) {
            float4 v = *(const float4*)((const float*)inV + zin + (long)(r0 + r) * C + c0 + tc);
            tile[r][tc+0] = f2b(v.x); tile[r][tc+1] = f2b(v.y);
            tile[r][tc+2] = f2b(v.z); tile[r][tc+3] = f2b(v.w);
        } else {
            ushort4 v = *(const ushort4*)((const u16*)inV + zin + (long)(r0 + r) * C + c0 + tc);
            tile[r][tc+0] = v.x; tile[r][tc+1] = v.y;
            tile[r][tc+2] = v.z; tile[r][tc+3] = v.w;
        }
    }
    __syncthreads();
    #pragma unroll
    for (int p = 0; p < 4; ++p) {
        const int rr = tr + p * 16;
        ushort4 o;
        o.x = tile[tc+0][rr]; o.y = tile[tc+1][rr];
        o.z = tile[tc+2][rr]; o.w = tile[tc+3][rr];
        *(ushort4*)(out + (long)blockIdx.z * R * C + (long)(c0 + rr) * R + r0 + tc) = o;
    }
}

// ---------------------------------------------------------------------------
// dispatch softmax over m, in place (fallback path)
__global__ __launch_bounds__(1024)
void softmax_m(float* __restrict__ logits)
{
    const int b   = blockIdx.y;
    const int c   = threadIdx.x & 15;
    const int col = blockIdx.x * 16 + c;
    const int mg  = threadIdx.x >> 4;
    float* base = logits + (long)b * 1048576 + col;

    float vals[16];
    float mx = -3.4e38f;
    #pragma unroll
    for (int i = 0; i < 16; ++i) {
        float v = base[(long)(mg * 16 + i) * 1024];
        vals[i] = v;
        mx = fmaxf(mx, v);
    }
    __shared__ float red[64][16];
    red[mg][c] = mx;
    __syncthreads();
    for (int s = 32; s >= 1; s >>= 1) {
        if (mg < s) red[mg][c] = fmaxf(red[mg][c], red[mg + s][c]);
        __syncthreads();
    }
    mx = red[0][c];
    __syncthreads();
    float ssum = 0.f;
    #pragma unroll
    for (int i = 0; i < 16; ++i) { vals[i] = expf(vals[i] - mx); ssum += vals[i]; }
    red[mg][c] = ssum;
    __syncthreads();
    for (int s = 32; s >= 1; s >>= 1) {
        if (mg < s) red[mg][c] += red[mg + s][c];
        __syncthreads();
    }
    const float inv = 1.f / red[0][c];
    #pragma unroll
    for (int i = 0; i < 16; ++i)
        base[(long)(mg * 16 + i) * 1024] = vals[i] * inv;
}

// dispatch softmax over m -> dispT[b][ep][m] bf16 (MFMA path; logits untouched)
__global__ __launch_bounds__(1024)
void softmax_mT(const float* __restrict__ logits, u16* __restrict__ dispT)
{
    const int b   = blockIdx.y;
    const int c   = threadIdx.x & 15;
    const int col = blockIdx.x * 16 + c;
    const int mg  = threadIdx.x >> 4;
    const float* base = logits + (long)b * 1048576 + col;

    float vals[16];
    float mx = -3.4e38f;
    #pragma unroll
    for (int i = 0; i < 16; ++i) {
        float v = base[(long)(mg * 16 + i) * 1024];
        vals[i] = v;
        mx = fmaxf(mx, v);
    }
    __shared__ float red[64][16];
    red[mg][c] = mx;
    __syncthreads();
    for (int s = 32; s >= 1; s >>= 1) {
        if (mg < s) red[mg][c] = fmaxf(red[mg][c], red[mg + s][c]);
        __syncthreads();
    }
    mx = red[0][c];
    __syncthreads();
    float ssum = 0.f;
    #pragma unroll
    for (int i = 0; i < 16; ++i) { vals[i] = expf(vals[i] - mx); ssum += vals[i]; }
    red[mg][c] = ssum;
    __syncthreads();
    for (int s = 32; s >= 1; s >>= 1) {
        if (mg < s) red[mg][c] += red[mg + s][c];
        __syncthreads();
    }
    const float inv = 1.f / red[0][c];

    union { u16 s[16]; uint4 q[2]; } pk;
    #pragma unroll
    for (int i = 0; i < 16; ++i) pk.s[i] = f2b(vals[i] * inv);
    u16* ob = dispT + (long)b * 1048576 + (long)col * 1024 + mg * 16;
    *(uint4*)ob       = pk.q[0];
    *(uint4*)(ob + 8) = pk.q[1];
}

// combine softmax over (e,p), + probabilities (fp32-exact) + argmax (fp32-exact)
template<bool B16>
__global__ __launch_bounds__(256)
void softmax_ep(const float* __restrict__ logits, void* __restrict__ comb,
                float* __restrict__ probs, float* __restrict__ tops)
{
    const long r = blockIdx.x;
    const int  t = threadIdx.x;
    const float* row = logits + r * 1024;
    float4 v = *(const float4*)(row + t * 4);

    float mx = fmaxf(fmaxf(v.x, v.y), fmaxf(v.z, v.w));
    #pragma unroll
    for (int s = 32; s; s >>= 1) mx = fmaxf(mx, __shfl_xor(mx, s));
    __shared__ float wr_[4];
    const int wid = t >> 6;
    if ((t & 63) == 0) wr_[wid] = mx;
    __syncthreads();
    mx = fmaxf(fmaxf(wr_[0], wr_[1]), fmaxf(wr_[2], wr_[3]));
    __syncthreads();

    float e0 = expf(v.x - mx), e1 = expf(v.y - mx);
    float e2 = expf(v.z - mx), e3 = expf(v.w - mx);
    float s4 = e0 + e1 + e2 + e3;
    float sm = s4;
    #pragma unroll
    for (int s = 32; s; s >>= 1) sm += __shfl_xor(sm, s);
    if ((t & 63) == 0) wr_[wid] = sm;
    __syncthreads();
    const float tot = wr_[0] + wr_[1] + wr_[2] + wr_[3];
    const float inv = 1.f / tot;

    if (B16) {
        ushort4 o;
        o.x = f2b(e0 * inv); o.y = f2b(e1 * inv);
        o.z = f2b(e2 * inv); o.w = f2b(e3 * inv);
        *(ushort4*)((u16*)comb + r * 1024 + t * 4) = o;
    } else {
        float4 o = make_float4(e0 * inv, e1 * inv, e2 * inv, e3 * inv);
        *(float4*)((float*)comb + r * 1024 + t * 4) = o;
    }

    __shared__ float es[16][16];
    es[t >> 4][t & 15] = s4 * inv;
    __syncthreads();
    __shared__ float pr[16];
    if (t < 16) {
        float ss = 0.f;
        #pragma unroll
        for (int i = 0; i < 16; ++i) ss += es[t][i];
        float p = ss * (1.f / 64.f);
        probs[r * 16 + t] = p;
        pr[t] = p;
    }
    __syncthreads();
    if (t == 0) {
        int best = 0; float bv = pr[0];
        #pragma unroll
        for (int e = 1; e < 16; ++e)
            if (pr[e] > bv) { bv = pr[e]; best = e; }
        tops[r] = (float)best;
    }
}

// ---------------------------------------------------------------------------
extern "C" void kernel_launch(void* const* d_in, const int* in_sizes, int n_in,
                              void* d_out, int out_size, void* d_ws, size_t ws_size,
                              hipStream_t stream)
{
    (void)in_sizes; (void)n_in; (void)out_size;
    const float* x   = (const float*)d_in[0];
    const float* phi = (const float*)d_in[1];
    const float* W1  = (const float*)d_in[2];
    const float* b1  = (const float*)d_in[3];
    const float* W2  = (const float*)d_in[4];
    const float* b2  = (const float*)d_in[5];

    float* outputs = (float*)d_out;
    float* probs   = outputs + 3145728;
    float* tops    = outputs + 3145728 + 65536;
    float* hid     = outputs + 3145728 + 65536 + 4096;   // [4][16][64][3072] fp32

    char* wsb = (char*)d_ws;

    if (ws_size >= 209715200ull) {
        // ================= MFMA path (needs 200 MiB ws) =================
        float* logits = (float*)(wsb);                    // 16 MiB
        u16*   combB  = (u16*)(wsb + 16777216);           // 8 MiB
        u16*   dispT  = (u16*)(wsb + 25165824);           // 8 MiB
        u16*   xT     = (u16*)(wsb + 33554432);           // 6 MiB
        u16*   mixB   = (u16*)(wsb + 39845888);           // 6 MiB
        u16*   W1T    = (u16*)(wsb + 46137344);           // 72 MiB
        u16*   W2T    = (u16*)(wsb + 121634816);          // 72 MiB
        u16*   eoutN  = (u16*)(wsb + 197132288);          // 6 MiB
        u16*   eoutT  = (u16*)(wsb + 203423744);          // 6 MiB

        // T1-T3: W1 -> W1T[e][f][d], W2 -> W2T[e][d][f], x -> xT[b][d][m]
        transpose_k<true><<<dim3(48, 12, 16), 256, 0, stream>>>(W1, W1T, 768, 3072);
        transpose_k<true><<<dim3(12, 48, 16), 256, 0, stream>>>(W2, W2T, 3072, 768);
        transpose_k<true><<<dim3(12, 16, 4),  256, 0, stream>>>(x,  xT,  1024, 768);

        // K1: logits = x @ phi (fp32 — keeps probabilities/argmax exact)
        gemm_k<false, false><<<dim3(16, 32, 1), 256, 0, stream>>>(
            x, phi, nullptr, logits,
            768, 768, 1024, 1024, 0L, 0L, 0L, 0, 64L * 768, 64L * 1024);

        // K2: combine softmax (bf16 comb + fp32 probs/tops); dispatch softmax -> dispT
        softmax_ep<true><<<dim3(4096), 256, 0, stream>>>(logits, combB, probs, tops);
        softmax_mT<<<dim3(64, 4), 1024, 0, stream>>>(logits, dispT);

        // K3: mix[b][ep][d] = dispT[b] @ x[b]  (M=1024,N=768,K=1024)
        mfma_gemm<false, false, false><<<dim3(6, 8, 4), 256, 0, stream>>>(
            dispT, xT, nullptr, mixB,
            1024, 1024, 1024, 768, 1048576L, 786432L, 786432L, 0,
            65536L, 49152L);

        // K4: hidden = gelu(mix @ W1 + b1) -> d_out fp32 (M=256,N=3072,K=768, z=e)
        mfma_gemm<false, true, true><<<dim3(24, 2, 16), 256, 0, stream>>>(
            mixB, W1T, b1, hid,
            768, 768, 768, 3072, 49152L, 2359296L, 196608L, 3072,
            786432L, 3145728L);

        // K5: eout = hidden @ W2 + b2 (A=fp32 from d_out; M=256,N=768,K=3072, z=e)
        mfma_gemm<true, false, false><<<dim3(6, 2, 16), 256, 0, stream>>>(
            hid, W2T, b2, eoutN,
            3072, 3072, 3072, 768, 196608L, 2359296L, 49152L, 768,
            3145728L, 786432L);

        // T4: eoutN[b][ep][d] -> eoutT[b][d][ep]
        transpose_k<false><<<dim3(12, 16, 4), 256, 0, stream>>>(eoutN, eoutT, 1024, 768);

        // K6: outputs[b] = combB[b] @ eoutT[b]  (M=1024,N=768,K=1024)
        mfma_gemm<false, false, true><<<dim3(6, 8, 4), 256, 0, stream>>>(
            combB, eoutT, nullptr, outputs,
            1024, 1024, 1024, 768, 1048576L, 786432L, 786432L, 0,
            65536L, 49152L);
    } else {
        // ================= fallback: round-1 fp32 path (44 MiB ws) =================
        float* logits = (float*)wsb;                  // becomes disp in place
        float* comb   = (float*)(wsb + 16777216);
        float* mixb   = (float*)(wsb + 33554432);
        float* eout   = (float*)wsb;                  // aliases dead disp

        gemm_k<false, false><<<dim3(16, 32, 1), 256, 0, stream>>>(
            x, phi, nullptr, logits,
            768, 768, 1024, 1024, 0L, 0L, 0L, 0, 64L * 768, 64L * 1024);
        softmax_ep<false><<<dim3(4096), 256, 0, stream>>>(logits, comb, probs, tops);
        softmax_m<<<dim3(64, 4), 1024, 0, stream>>>(logits);
        gemm_k<true, false><<<dim3(12, 8, 4), 256, 0, stream>>>(
            logits, x, nullptr, mixb,
            1024, 1024, 768, 768, 1048576L, 786432L, 786432L, 0, 0L, 64L * 768);
        gemm_k<false, true><<<dim3(48, 2, 16), 256, 0, stream>>>(
            mixb, W1, b1, hid,
            768, 768, 3072, 3072, 49152L, 2359296L, 196608L, 3072,
            786432L, 3145728L);
        gemm_k<false, false><<<dim3(12, 2, 16), 256, 0, stream>>>(
            hid, W2, b2, eout,
            3072, 3072, 768, 768, 196608L, 2359296L, 49152L, 768,
            3145728L, 786432L);
        gemm_k<false, false><<<dim3(12, 8, 4), 256, 0, stream>>>(
            comb, eout, nullptr, outputs,
            1024, 1024, 768, 768, 1048576L, 786432L, 786432L, 0,
            64L * 1024, 64L * 768);
    }
}

// Round 2
// 660.476 us; speedup vs baseline: 1.0494x; 1.0494x over previous
//
#include <hip/hip_runtime.h>
#include <hip/hip_bf16.h>

// SoftMoE: B=4, M=1024, D=768, E=16, P=64, F=3072, EP=1024, rows=B*M=4096
// d_out (fp32): outputs[4,1024,768] | probs[4,1024,16] | tops[4,1024,1] | hidden[4,16,64,3072]

typedef unsigned short u16;
typedef __bf16 bf16x8 __attribute__((ext_vector_type(8)));
typedef float f32x4 __attribute__((ext_vector_type(4)));

__device__ __forceinline__ float gelu_f(float x) {
    const float c = 0.7978845608028654f;  // sqrt(2/pi)
    float u = c * (x + 0.044715f * x * x * x);
    return 0.5f * x * (1.0f + tanhf(u));
}

__device__ __forceinline__ u16 f2b(float x) {
    union { float f; unsigned u; } v; v.f = x;
    unsigned r = v.u + 0x7FFF + ((v.u >> 16) & 1);
    return (u16)(r >> 16);
}

// ---------------------------------------------------------------------------
// fp32 GEMM (round-1, proven). Used for K1 always; K3-K6 on the fallback path.
// addr = z*aZ + (row>>6)*rgs + (row&63)*ld + k
template<bool TRANSA, bool DOGELU>
__global__ __launch_bounds__(256)
void gemm_k(const float* __restrict__ A, const float* __restrict__ Bm,
            const float* __restrict__ bias, float* __restrict__ C,
            int K, int lda, int ldb, int ldc,
            long aZ, long bZ, long cZ, int biasZ,
            long rgsA, long rgsC)
{
    __shared__ float As[16][128];
    __shared__ float Bs[16][64];
    const int z = blockIdx.z;
    A  += (long)z * aZ;
    Bm += (long)z * bZ;
    if (bias) bias += (long)z * biasZ;
    const int row0 = blockIdx.y * 128;
    const int col0 = blockIdx.x * 64;
    const int t  = threadIdx.x;
    const int tx = t & 15;
    const int ty = t >> 4;

    float acc[8][4];
    #pragma unroll
    for (int i = 0; i < 8; ++i)
        #pragma unroll
        for (int j = 0; j < 4; ++j) acc[i][j] = 0.f;

    for (int k0 = 0; k0 < K; k0 += 16) {
        if (TRANSA) {
            const int kk = t >> 5;
            const int ii = (t & 31) * 4;
            const float* pa = A + (long)(k0 + kk) * lda + (row0 + ii);
            float4 v0 = *(const float4*)pa;
            float4 v1 = *(const float4*)(pa + 8L * lda);
            *(float4*)&As[kk][ii]     = v0;
            *(float4*)&As[kk + 8][ii] = v1;
        } else {
            const int ii = t >> 1;
            const int kk = (t & 1) * 8;
            const int grow = row0 + ii;
            const float* pa = A + (long)(grow >> 6) * rgsA
                                + (long)(grow & 63) * lda + (k0 + kk);
            float4 v0 = *(const float4*)pa;
            float4 v1 = *(const float4*)(pa + 4);
            As[kk+0][ii] = v0.x; As[kk+1][ii] = v0.y;
            As[kk+2][ii] = v0.z; As[kk+3][ii] = v0.w;
            As[kk+4][ii] = v1.x; As[kk+5][ii] = v1.y;
            As[kk+6][ii] = v1.z; As[kk+7][ii] = v1.w;
        }
        {
            const int kk = t >> 4;
            const int jj = (t & 15) * 4;
            float4 v = *(const float4*)(Bm + (long)(k0 + kk) * ldb + (col0 + jj));
            *(float4*)&Bs[kk][jj] = v;
        }
        __syncthreads();
        #pragma unroll
        for (int k = 0; k < 16; ++k) {
            float a[8], b[4];
            *(float4*)&a[0] = *(const float4*)&As[k][ty * 8];
            *(float4*)&a[4] = *(const float4*)&As[k][ty * 8 + 4];
            *(float4*)&b[0] = *(const float4*)&Bs[k][tx * 4];
            #pragma unroll
            for (int i = 0; i < 8; ++i)
                #pragma unroll
                for (int j = 0; j < 4; ++j)
                    acc[i][j] = fmaf(a[i], b[j], acc[i][j]);
        }
        __syncthreads();
    }

    float bj[4] = {0.f, 0.f, 0.f, 0.f};
    if (bias) {
        #pragma unroll
        for (int j = 0; j < 4; ++j) bj[j] = bias[col0 + tx * 4 + j];
    }
    #pragma unroll
    for (int i = 0; i < 8; ++i) {
        const int grow = row0 + ty * 8 + i;
        const long rb = (long)(grow >> 6) * rgsC
                      + (long)(grow & 63) * ldc + (col0 + tx * 4);
        float rv[4];
        #pragma unroll
        for (int j = 0; j < 4; ++j) {
            float v = acc[i][j] + bj[j];
            if (DOGELU) v = gelu_f(v);
            rv[j] = v;
        }
        *(float4*)(C + (long)z * cZ + rb) = make_float4(rv[0], rv[1], rv[2], rv[3]);
    }
}

// ---------------------------------------------------------------------------
// bf16 MFMA GEMM. 128x128 tile, BK=64, 256 thr = 4 waves (2x2), 64x64/wave as
// 4x4 of v_mfma_f32_16x16x32_bf16. LDS [dim][64] bf16 with XOR chunk swizzle
// (chunk ^= row&7) -> conflict-free b128 staging writes AND fragment reads.
// A: bf16 or fp32 (converted in staging), grouped rows. B: bf16 [n][k].
//
// Grid is FLATTENED 1-D with an XCD-grouping swizzle: assuming XCD = flat%8
// (round-robin dispatch), virtual rank r = (flat&7)*nper + (flat>>3) packs
// consecutive r (same expert z) onto the SAME XCD so the per-z A panel
// (~1.6 MB) stays L2-resident across its col-tile re-reads.
template<bool AF32, bool DOGELU, bool CF32>
__global__ __launch_bounds__(256)
void mfma_gemm(const void* __restrict__ Av, const u16* __restrict__ Bt,
               const float* __restrict__ bias, void* __restrict__ Cv,
               int K, int lda, int ldb, int ldc,
               long aZ, long bZ, long cZ, int biasZ,
               long rgsA, long rgsC, int nbx, int nblk)
{
    __shared__ u16 As[128][64];
    __shared__ u16 Bs[128][64];
    // --- XCD-grouping block-id swizzle (bijective; gridDim.x % 8 == 0) ---
    const int flat = blockIdx.x;
    const int nper = gridDim.x >> 3;
    const int r    = (flat & 7) * nper + (flat >> 3);
    const int z    = r / nblk;
    const int bi   = r - z * nblk;
    const int by   = bi / nbx;
    const int bx   = bi - by * nbx;

    const int row0 = by * 128;
    const int col0 = bx * 128;
    const int t    = threadIdx.x;
    const int lane = t & 63;
    const int wave = t >> 6;
    const int wr   = (wave >> 1) * 64;
    const int wc   = (wave & 1) * 64;

    const int srow  = t >> 1;   // staging row 0..127
    const int shalf = t & 1;    // which 32-elem k half
    const int agrow = row0 + srow;
    const long aRowOff = (long)z * aZ + (long)(agrow >> 6) * rgsA
                       + (long)(agrow & 63) * lda;
    const long bRowOff = (long)z * bZ + (long)(col0 + srow) * ldb;

    f32x4 acc[4][4] = {};

    for (int k0 = 0; k0 < K; k0 += 64) {
        // --- stage A ---
        if (AF32) {
            const float* pa = (const float*)Av + aRowOff + k0 + shalf * 32;
            #pragma unroll
            for (int q = 0; q < 4; ++q) {
                float4 u0 = *(const float4*)(pa + q * 8);
                float4 u1 = *(const float4*)(pa + q * 8 + 4);
                u16 tmp[8] = { f2b(u0.x), f2b(u0.y), f2b(u0.z), f2b(u0.w),
                               f2b(u1.x), f2b(u1.y), f2b(u1.z), f2b(u1.w) };
                const int cs = (shalf * 4 + q) ^ (srow & 7);
                *(uint4*)&As[srow][cs * 8] = *(const uint4*)tmp;
            }
        } else {
            const u16* pa = (const u16*)Av + aRowOff + k0 + shalf * 32;
            #pragma unroll
            for (int q = 0; q < 4; ++q) {
                uint4 v = *(const uint4*)(pa + q * 8);
                const int cs = (shalf * 4 + q) ^ (srow & 7);
                *(uint4*)&As[srow][cs * 8] = v;
            }
        }
        // --- stage B (always bf16 [n][k]) ---
        {
            const u16* pb = Bt + bRowOff + k0 + shalf * 32;
            #pragma unroll
            for (int q = 0; q < 4; ++q) {
                uint4 v = *(const uint4*)(pb + q * 8);
                const int cs = (shalf * 4 + q) ^ (srow & 7);
                *(uint4*)&Bs[srow][cs * 8] = v;
            }
        }
        __syncthreads();

        #pragma unroll
        for (int kk = 0; kk < 2; ++kk) {
            const int cchunk = kk * 4 + (lane >> 4);   // k chunk 0..7
            bf16x8 af[4], bfr[4];
            #pragma unroll
            for (int i = 0; i < 4; ++i) {
                const int m = wr + i * 16 + (lane & 15);
                af[i]  = __builtin_bit_cast(bf16x8,
                           *(const uint4*)&As[m][(cchunk ^ (m & 7)) * 8]);
                const int n = wc + i * 16 + (lane & 15);
                bfr[i] = __builtin_bit_cast(bf16x8,
                           *(const uint4*)&Bs[n][(cchunk ^ (n & 7)) * 8]);
            }
            #pragma unroll
            for (int i = 0; i < 4; ++i)
                #pragma unroll
                for (int j = 0; j < 4; ++j)
                    acc[i][j] = __builtin_amdgcn_mfma_f32_16x16x32_bf16(
                                    af[i], bfr[j], acc[i][j], 0, 0, 0);
        }
        __syncthreads();
    }

    // --- epilogue: C/D layout col=lane&15, row=(lane>>4)*4+reg ---
    const int cq = lane >> 4;
    #pragma unroll
    for (int j = 0; j < 4; ++j) {
        const int gcol = col0 + wc + j * 16 + (lane & 15);
        const float bv = bias ? bias[(long)z * biasZ + gcol] : 0.f;
        #pragma unroll
        for (int i = 0; i < 4; ++i) {
            #pragma unroll
            for (int r2 = 0; r2 < 4; ++r2) {
                const int grow = row0 + wr + i * 16 + cq * 4 + r2;
                const long co = (long)z * cZ + (long)(grow >> 6) * rgsC
                              + (long)(grow & 63) * ldc + gcol;
                float v = acc[i][j][r2] + bv;
                if (DOGELU) v = gelu_f(v);
                if (CF32) ((float*)Cv)[co] = v;
                else      ((u16*)Cv)[co]  = f2b(v);
            }
        }
    }
}

// ---------------------------------------------------------------------------
// Elementwise fp32 -> bf16 convert (8 elems/thread). n must be /8/256.
__global__ __launch_bounds__(256)
void f32_to_b16(const float* __restrict__ in, u16* __restrict__ out)
{
    const long i = ((long)blockIdx.x * 256 + threadIdx.x) * 8;
    float4 a = *(const float4*)(in + i);
    float4 b = *(const float4*)(in + i + 4);
    u16 tmp[8] = { f2b(a.x), f2b(a.y), f2b(a.z), f2b(a.w),
                   f2b(b.x), f2b(b.y), f2b(b.z), f2b(b.w) };
    *(uint4*)(out + i) = *(const uint4*)tmp;
}

// ---------------------------------------------------------------------------
// Transpose [z][R][C] (fp32 or bf16) -> [z][C][R] bf16. 64x64 tiles, 256 thr.
template<bool F32>
__global__ __launch_bounds__(256)
void transpose_k(const void* __restrict__ inV, u16* __restrict__ out, int R, int C)
{
    __shared__ u16 tile[64][72];
    const long zin = (long)blockIdx.z * R * C;
    const int r0 = blockIdx.y * 64, c0 = blockIdx.x * 64;
    const int t  = threadIdx.x;
    const int tr = t >> 4;
    const int tc = (t & 15) * 4;
    #pragma unroll
    for (int p = 0; p < 4; ++p) {
        const int r = tr + p * 16;
        if (F32) {
            float4 v = *(const float4*)((const float*)inV + zin + (long)(r0 + r) * C + c0 + tc);
            tile[r][tc+0] = f2b(v.x); tile[r][tc+1] = f2b(v.y);
            tile[r][tc+2] = f2b(v.z); tile[r][tc+3] = f2b(v.w);
        } else {
            ushort4 v = *(const ushort4*)((const u16*)inV + zin + (long)(r0 + r) * C + c0 + tc);
            tile[r][tc+0] = v.x; tile[r][tc+1] = v.y;
            tile[r][tc+2] = v.z; tile[r][tc+3] = v.w;
        }
    }
    __syncthreads();
    #pragma unroll
    for (int p = 0; p < 4; ++p) {
        const int rr = tr + p * 16;
        ushort4 o;
        o.x = tile[tc+0][rr]; o.y = tile[tc+1][rr];
        o.z = tile[tc+2][rr]; o.w = tile[tc+3][rr];
        *(ushort4*)(out + (long)blockIdx.z * R * C + (long)(c0 + rr) * R + r0 + tc) = o;
    }
}

// ---------------------------------------------------------------------------
// dispatch softmax over m, in place (fallback path)
__global__ __launch_bounds__(1024)
void softmax_m(float* __restrict__ logits)
{
    const int b   = blockIdx.y;
    const int c   = threadIdx.x & 15;
    const int col = blockIdx.x * 16 + c;
    const int mg  = threadIdx.x >> 4;
    float* base = logits + (long)b * 1048576 + col;

    float vals[16];
    float mx = -3.4e38f;
    #pragma unroll
    for (int i = 0; i < 16; ++i) {
        float v = base[(long)(mg * 16 + i) * 1024];
        vals[i] = v;
        mx = fmaxf(mx, v);
    }
    __shared__ float red[64][16];
    red[mg][c] = mx;
    __syncthreads();
    for (int s = 32; s >= 1; s >>= 1) {
        if (mg < s) red[mg][c] = fmaxf(red[mg][c], red[mg + s][c]);
        __syncthreads();
    }
    mx = red[0][c];
    __syncthreads();
    float ssum = 0.f;
    #pragma unroll
    for (int i = 0; i < 16; ++i) { vals[i] = expf(vals[i] - mx); ssum += vals[i]; }
    red[mg][c] = ssum;
    __syncthreads();
    for (int s = 32; s >= 1; s >>= 1) {
        if (mg < s) red[mg][c] += red[mg + s][c];
        __syncthreads();
    }
    const float inv = 1.f / red[0][c];
    #pragma unroll
    for (int i = 0; i < 16; ++i)
        base[(long)(mg * 16 + i) * 1024] = vals[i] * inv;
}

// dispatch softmax over m -> dispT[b][ep][m] bf16 (MFMA path; logits untouched)
__global__ __launch_bounds__(1024)
void softmax_mT(const float* __restrict__ logits, u16* __restrict__ dispT)
{
    const int b   = blockIdx.y;
    const int c   = threadIdx.x & 15;
    const int col = blockIdx.x * 16 + c;
    const int mg  = threadIdx.x >> 4;
    const float* base = logits + (long)b * 1048576 + col;

    float vals[16];
    float mx = -3.4e38f;
    #pragma unroll
    for (int i = 0; i < 16; ++i) {
        float v = base[(long)(mg * 16 + i) * 1024];
        vals[i] = v;
        mx = fmaxf(mx, v);
    }
    __shared__ float red[64][16];
    red[mg][c] = mx;
    __syncthreads();
    for (int s = 32; s >= 1; s >>= 1) {
        if (mg < s) red[mg][c] = fmaxf(red[mg][c], red[mg + s][c]);
        __syncthreads();
    }
    mx = red[0][c];
    __syncthreads();
    float ssum = 0.f;
    #pragma unroll
    for (int i = 0; i < 16; ++i) { vals[i] = expf(vals[i] - mx); ssum += vals[i]; }
    red[mg][c] = ssum;
    __syncthreads();
    for (int s = 32; s >= 1; s >>= 1) {
        if (mg < s) red[mg][c] += red[mg + s][c];
        __syncthreads();
    }
    const float inv = 1.f / red[0][c];

    union { u16 s[16]; uint4 q[2]; } pk;
    #pragma unroll
    for (int i = 0; i < 16; ++i) pk.s[i] = f2b(vals[i] * inv);
    u16* ob = dispT + (long)b * 1048576 + (long)col * 1024 + mg * 16;
    *(uint4*)ob       = pk.q[0];
    *(uint4*)(ob + 8) = pk.q[1];
}

// combine softmax over (e,p), + probabilities (fp32-exact) + argmax (fp32-exact)
template<bool B16>
__global__ __launch_bounds__(256)
void softmax_ep(const float* __restrict__ logits, void* __restrict__ comb,
                float* __restrict__ probs, float* __restrict__ tops)
{
    const long r = blockIdx.x;
    const int  t = threadIdx.x;
    const float* row = logits + r * 1024;
    float4 v = *(const float4*)(row + t * 4);

    float mx = fmaxf(fmaxf(v.x, v.y), fmaxf(v.z, v.w));
    #pragma unroll
    for (int s = 32; s; s >>= 1) mx = fmaxf(mx, __shfl_xor(mx, s));
    __shared__ float wr_[4];
    const int wid = t >> 6;
    if ((t & 63) == 0) wr_[wid] = mx;
    __syncthreads();
    mx = fmaxf(fmaxf(wr_[0], wr_[1]), fmaxf(wr_[2], wr_[3]));
    __syncthreads();

    float e0 = expf(v.x - mx), e1 = expf(v.y - mx);
    float e2 = expf(v.z - mx), e3 = expf(v.w - mx);
    float s4 = e0 + e1 + e2 + e3;
    float sm = s4;
    #pragma unroll
    for (int s = 32; s; s >>= 1) sm += __shfl_xor(sm, s);
    if ((t & 63) == 0) wr_[wid] = sm;
    __syncthreads();
    const float tot = wr_[0] + wr_[1] + wr_[2] + wr_[3];
    const float inv = 1.f / tot;

    if (B16) {
        ushort4 o;
        o.x = f2b(e0 * inv); o.y = f2b(e1 * inv);
        o.z = f2b(e2 * inv); o.w = f2b(e3 * inv);
        *(ushort4*)((u16*)comb + r * 1024 + t * 4) = o;
    } else {
        float4 o = make_float4(e0 * inv, e1 * inv, e2 * inv, e3 * inv);
        *(float4*)((float*)comb + r * 1024 + t * 4) = o;
    }

    __shared__ float es[16][16];
    es[t >> 4][t & 15] = s4 * inv;
    __syncthreads();
    __shared__ float pr[16];
    if (t < 16) {
        float ss = 0.f;
        #pragma unroll
        for (int i = 0; i < 16; ++i) ss += es[t][i];
        float p = ss * (1.f / 64.f);
        probs[r * 16 + t] = p;
        pr[t] = p;
    }
    __syncthreads();
    if (t == 0) {
        int best = 0; float bv = pr[0];
        #pragma unroll
        for (int e = 1; e < 16; ++e)
            if (pr[e] > bv) { bv = pr[e]; best = e; }
        tops[r] = (float)best;
    }
}

// ---------------------------------------------------------------------------
extern "C" void kernel_launch(void* const* d_in, const int* in_sizes, int n_in,
                              void* d_out, int out_size, void* d_ws, size_t ws_size,
                              hipStream_t stream)
{
    (void)in_sizes; (void)n_in; (void)out_size;
    const float* x   = (const float*)d_in[0];
    const float* phi = (const float*)d_in[1];
    const float* W1  = (const float*)d_in[2];
    const float* b1  = (const float*)d_in[3];
    const float* W2  = (const float*)d_in[4];
    const float* b2  = (const float*)d_in[5];

    float* outputs = (float*)d_out;
    float* probs   = outputs + 3145728;
    float* tops    = outputs + 3145728 + 65536;
    float* hid     = outputs + 3145728 + 65536 + 4096;   // [4][16][64][3072] fp32

    char* wsb = (char*)d_ws;

    if (ws_size >= 209715200ull) {
        // ================= MFMA path (needs 200 MiB ws) =================
        float* logits = (float*)(wsb);                    // 16 MiB
        u16*   combB  = (u16*)(wsb + 16777216);           // 8 MiB
        u16*   dispT  = (u16*)(wsb + 25165824);           // 8 MiB
        u16*   xT     = (u16*)(wsb + 33554432);           // 6 MiB
        u16*   mixB   = (u16*)(wsb + 39845888);           // 6 MiB
        u16*   W1T    = (u16*)(wsb + 46137344);           // 72 MiB (dead after K4)
        u16*   W2T    = (u16*)(wsb + 121634816);          // 72 MiB
        u16*   eoutN  = (u16*)(wsb + 197132288);          // 6 MiB
        u16*   eoutT  = (u16*)(wsb + 203423744);          // 6 MiB
        u16*   hidB   = W1T;                              // 24 MiB, aliases dead W1T

        // T1-T3: W1 -> W1T[e][f][d], W2 -> W2T[e][d][f], x -> xT[b][d][m]
        transpose_k<true><<<dim3(48, 12, 16), 256, 0, stream>>>(W1, W1T, 768, 3072);
        transpose_k<true><<<dim3(12, 48, 16), 256, 0, stream>>>(W2, W2T, 3072, 768);
        transpose_k<true><<<dim3(12, 16, 4),  256, 0, stream>>>(x,  xT,  1024, 768);

        // K1: logits = x @ phi (fp32 — keeps probabilities/argmax exact)
        gemm_k<false, false><<<dim3(16, 32, 1), 256, 0, stream>>>(
            x, phi, nullptr, logits,
            768, 768, 1024, 1024, 0L, 0L, 0L, 0, 64L * 768, 64L * 1024);

        // K2: combine softmax (bf16 comb + fp32 probs/tops); dispatch softmax -> dispT
        softmax_ep<true><<<dim3(4096), 256, 0, stream>>>(logits, combB, probs, tops);
        softmax_mT<<<dim3(64, 4), 1024, 0, stream>>>(logits, dispT);

        // K3: mix[b][ep][d] = dispT[b] @ x[b]  (M=1024,N=768,K=1024), z=b
        mfma_gemm<false, false, false><<<dim3(192), 256, 0, stream>>>(
            dispT, xT, nullptr, mixB,
            1024, 1024, 1024, 768, 1048576L, 786432L, 786432L, 0,
            65536L, 49152L, 6, 48);

        // K4: hidden = gelu(mix @ W1 + b1) -> d_out fp32 (M=256,N=3072,K=768, z=e)
        mfma_gemm<false, true, true><<<dim3(768), 256, 0, stream>>>(
            mixB, W1T, b1, hid,
            768, 768, 768, 3072, 49152L, 2359296L, 196608L, 3072,
            786432L, 3145728L, 24, 48);

        // C1: hid fp32 -> hidB bf16 (W1T dead now; 12.6M elems / 8 / 256 = 6144 blocks)
        f32_to_b16<<<dim3(6144), 256, 0, stream>>>(hid, hidB);

        // K5: eout = hidden @ W2 + b2 (A=bf16 hidB; M=256,N=768,K=3072, z=e)
        mfma_gemm<false, false, false><<<dim3(192), 256, 0, stream>>>(
            hidB, W2T, b2, eoutN,
            3072, 3072, 3072, 768, 196608L, 2359296L, 49152L, 768,
            3145728L, 786432L, 6, 12);

        // T4: eoutN[b][ep][d] -> eoutT[b][d][ep]
        transpose_k<false><<<dim3(12, 16, 4), 256, 0, stream>>>(eoutN, eoutT, 1024, 768);

        // K6: outputs[b] = combB[b] @ eoutT[b]  (M=1024,N=768,K=1024), z=b
        mfma_gemm<false, false, true><<<dim3(192), 256, 0, stream>>>(
            combB, eoutT, nullptr, outputs,
            1024, 1024, 1024, 768, 1048576L, 786432L, 786432L, 0,
            65536L, 49152L, 6, 48);
    } else {
        // ================= fallback: round-1 fp32 path (44 MiB ws) =================
        float* logits = (float*)wsb;                  // becomes disp in place
        float* comb   = (float*)(wsb + 16777216);
        float* mixb   = (float*)(wsb + 33554432);
        float* eout   = (float*)wsb;                  // aliases dead disp

        gemm_k<false, false><<<dim3(16, 32, 1), 256, 0, stream>>>(
            x, phi, nullptr, logits,
            768, 768, 1024, 1024, 0L, 0L, 0L, 0, 64L * 768, 64L * 1024);
        softmax_ep<false><<<dim3(4096), 256, 0, stream>>>(logits, comb, probs, tops);
        softmax_m<<<dim3(64, 4), 1024, 0, stream>>>(logits);
        gemm_k<true, false><<<dim3(12, 8, 4), 256, 0, stream>>>(
            logits, x, nullptr, mixb,
            1024, 1024, 768, 768, 1048576L, 786432L, 786432L, 0, 0L, 64L * 768);
        gemm_k<false, true><<<dim3(48, 2, 16), 256, 0, stream>>>(
            mixb, W1, b1, hid,
            768, 768, 3072, 3072, 49152L, 2359296L, 196608L, 3072,
            786432L, 3145728L);
        gemm_k<false, false><<<dim3(12, 2, 16), 256, 0, stream>>>(
            hid, W2, b2, eout,
            3072, 3072, 768, 768, 196608L, 2359296L, 49152L, 768,
            3145728L, 786432L);
        gemm_k<false, false><<<dim3(12, 8, 4), 256, 0, stream>>>(
            comb, eout, nullptr, outputs,
            1024, 1024, 768, 768, 1048576L, 786432L, 786432L, 0,
            64L * 1024, 64L * 768);
    }
}

// Round 3
// 649.773 us; speedup vs baseline: 1.0667x; 1.0165x over previous
//
#include <hip/hip_runtime.h>
#include <hip/hip_bf16.h>

// SoftMoE: B=4, M=1024, D=768, E=16, P=64, F=3072, EP=1024, rows=B*M=4096
// d_out (fp32): outputs[4,1024,768] | probs[4,1024,16] | tops[4,1024,1] | hidden[4,16,64,3072]

typedef unsigned short u16;
typedef __bf16 bf16x8 __attribute__((ext_vector_type(8)));
typedef float f32x4 __attribute__((ext_vector_type(4)));

__device__ __forceinline__ float gelu_f(float x) {
    const float c = 0.7978845608028654f;  // sqrt(2/pi)
    float u = c * (x + 0.044715f * x * x * x);
    return 0.5f * x * (1.0f + tanhf(u));
}

__device__ __forceinline__ u16 f2b(float x) {
    union { float f; unsigned u; } v; v.f = x;
    unsigned r = v.u + 0x7FFF + ((v.u >> 16) & 1);
    return (u16)(r >> 16);
}

// ---------------------------------------------------------------------------
// K1 logits GEMM, fp32 (argmax/probs need fp32-exact logits; no fp32 MFMA).
// 128x128 tile, 512 thr (8 waves = 2/SIMD), BK=16, register-prefetch double
// buffer (global loads for tile k+1 issued before compute on tile k -> L3
// latency hidden). A staged transposed [k][row] w/ pad 132 (2-way only);
// B plain [k][128], per-thread cols tx*4 and 64+tx*4 (2-way only).
// Grid: dim3(1024/128, 4096/128) = (8, 32) = 256 blocks = 1 block/CU.
__global__ __launch_bounds__(512)
void gemm_logits(const float* __restrict__ x, const float* __restrict__ phi,
                 float* __restrict__ C)
{
    __shared__ float As[2][16][132];
    __shared__ float Bs[2][16][128];
    const int col0 = blockIdx.x * 128;
    const int row0 = blockIdx.y * 128;
    const int t = threadIdx.x;

    const int arow = t >> 2, akk = (t & 3) * 4;     // A staging map
    const int bkk  = t >> 5, bcc = (t & 31) * 4;    // B staging map
    const float* pa = x   + (long)(row0 + arow) * 768 + akk;
    const float* pb = phi + (long)bkk * 1024 + col0 + bcc;

    const int ty = t >> 4, tx = t & 15;             // compute map

    float acc[4][8];
    #pragma unroll
    for (int i = 0; i < 4; ++i)
        #pragma unroll
        for (int j = 0; j < 8; ++j) acc[i][j] = 0.f;

    float4 ra = *(const float4*)pa;
    float4 rb = *(const float4*)pb;
    As[0][akk+0][arow] = ra.x;
    As[0][akk+1][arow] = ra.y;
    As[0][akk+2][arow] = ra.z;
    As[0][akk+3][arow] = ra.w;
    *(float4*)&Bs[0][bkk][bcc] = rb;

    int cur = 0;
    for (int kt = 0; kt < 48; ++kt) {
        if (kt + 1 < 48) {
            ra = *(const float4*)(pa + (kt + 1) * 16);
            rb = *(const float4*)(pb + (long)(kt + 1) * 16 * 1024);
        }
        __syncthreads();
        #pragma unroll
        for (int k = 0; k < 16; ++k) {
            float a[4], bl[4], bh[4];
            *(float4*)a  = *(const float4*)&As[cur][k][ty * 4];
            *(float4*)bl = *(const float4*)&Bs[cur][k][tx * 4];
            *(float4*)bh = *(const float4*)&Bs[cur][k][64 + tx * 4];
            #pragma unroll
            for (int i = 0; i < 4; ++i) {
                #pragma unroll
                for (int j = 0; j < 4; ++j) {
                    acc[i][j]     = fmaf(a[i], bl[j], acc[i][j]);
                    acc[i][j + 4] = fmaf(a[i], bh[j], acc[i][j + 4]);
                }
            }
        }
        if (kt + 1 < 48) {
            const int nxt = cur ^ 1;
            As[nxt][akk+0][arow] = ra.x;
            As[nxt][akk+1][arow] = ra.y;
            As[nxt][akk+2][arow] = ra.z;
            As[nxt][akk+3][arow] = ra.w;
            *(float4*)&Bs[nxt][bkk][bcc] = rb;
            cur = nxt;
        }
    }

    #pragma unroll
    for (int i = 0; i < 4; ++i) {
        const long ro = (long)(row0 + ty * 4 + i) * 1024 + col0;
        *(float4*)&C[ro + tx * 4] =
            make_float4(acc[i][0], acc[i][1], acc[i][2], acc[i][3]);
        *(float4*)&C[ro + 64 + tx * 4] =
            make_float4(acc[i][4], acc[i][5], acc[i][6], acc[i][7]);
    }
}

// ---------------------------------------------------------------------------
// fp32 GEMM (round-1, proven). Fallback path only.
template<bool TRANSA, bool DOGELU>
__global__ __launch_bounds__(256)
void gemm_k(const float* __restrict__ A, const float* __restrict__ Bm,
            const float* __restrict__ bias, float* __restrict__ C,
            int K, int lda, int ldb, int ldc,
            long aZ, long bZ, long cZ, int biasZ,
            long rgsA, long rgsC)
{
    __shared__ float As[16][128];
    __shared__ float Bs[16][64];
    const int z = blockIdx.z;
    A  += (long)z * aZ;
    Bm += (long)z * bZ;
    if (bias) bias += (long)z * biasZ;
    const int row0 = blockIdx.y * 128;
    const int col0 = blockIdx.x * 64;
    const int t  = threadIdx.x;
    const int tx = t & 15;
    const int ty = t >> 4;

    float acc[8][4];
    #pragma unroll
    for (int i = 0; i < 8; ++i)
        #pragma unroll
        for (int j = 0; j < 4; ++j) acc[i][j] = 0.f;

    for (int k0 = 0; k0 < K; k0 += 16) {
        if (TRANSA) {
            const int kk = t >> 5;
            const int ii = (t & 31) * 4;
            const float* pa = A + (long)(k0 + kk) * lda + (row0 + ii);
            float4 v0 = *(const float4*)pa;
            float4 v1 = *(const float4*)(pa + 8L * lda);
            *(float4*)&As[kk][ii]     = v0;
            *(float4*)&As[kk + 8][ii] = v1;
        } else {
            const int ii = t >> 1;
            const int kk = (t & 1) * 8;
            const int grow = row0 + ii;
            const float* pa = A + (long)(grow >> 6) * rgsA
                                + (long)(grow & 63) * lda + (k0 + kk);
            float4 v0 = *(const float4*)pa;
            float4 v1 = *(const float4*)(pa + 4);
            As[kk+0][ii] = v0.x; As[kk+1][ii] = v0.y;
            As[kk+2][ii] = v0.z; As[kk+3][ii] = v0.w;
            As[kk+4][ii] = v1.x; As[kk+5][ii] = v1.y;
            As[kk+6][ii] = v1.z; As[kk+7][ii] = v1.w;
        }
        {
            const int kk = t >> 4;
            const int jj = (t & 15) * 4;
            float4 v = *(const float4*)(Bm + (long)(k0 + kk) * ldb + (col0 + jj));
            *(float4*)&Bs[kk][jj] = v;
        }
        __syncthreads();
        #pragma unroll
        for (int k = 0; k < 16; ++k) {
            float a[8], b[4];
            *(float4*)&a[0] = *(const float4*)&As[k][ty * 8];
            *(float4*)&a[4] = *(const float4*)&As[k][ty * 8 + 4];
            *(float4*)&b[0] = *(const float4*)&Bs[k][tx * 4];
            #pragma unroll
            for (int i = 0; i < 8; ++i)
                #pragma unroll
                for (int j = 0; j < 4; ++j)
                    acc[i][j] = fmaf(a[i], b[j], acc[i][j]);
        }
        __syncthreads();
    }

    float bj[4] = {0.f, 0.f, 0.f, 0.f};
    if (bias) {
        #pragma unroll
        for (int j = 0; j < 4; ++j) bj[j] = bias[col0 + tx * 4 + j];
    }
    #pragma unroll
    for (int i = 0; i < 8; ++i) {
        const int grow = row0 + ty * 8 + i;
        const long rb = (long)(grow >> 6) * rgsC
                      + (long)(grow & 63) * ldc + (col0 + tx * 4);
        float rv[4];
        #pragma unroll
        for (int j = 0; j < 4; ++j) {
            float v = acc[i][j] + bj[j];
            if (DOGELU) v = gelu_f(v);
            rv[j] = v;
        }
        *(float4*)(C + (long)z * cZ + rb) = make_float4(rv[0], rv[1], rv[2], rv[3]);
    }
}

// ---------------------------------------------------------------------------
// bf16 MFMA GEMM. 128x128 tile, BK=64, 256 thr = 4 waves (2x2), 64x64/wave as
// 4x4 of v_mfma_f32_16x16x32_bf16. LDS [dim][64] bf16 with XOR chunk swizzle.
// Grid flattened 1-D with XCD-grouping swizzle (r = (flat&7)*nper + flat>>3)
// so each expert's blocks share an XCD -> A panel L2-resident.
// Optional dual output: Cb2 != nullptr writes bf16 copy at same indices.
template<bool AF32, bool DOGELU, bool CF32>
__global__ __launch_bounds__(256)
void mfma_gemm(const void* __restrict__ Av, const u16* __restrict__ Bt,
               const float* __restrict__ bias, void* __restrict__ Cv,
               u16* __restrict__ Cb2,
               int K, int lda, int ldb, int ldc,
               long aZ, long bZ, long cZ, int biasZ,
               long rgsA, long rgsC, int nbx, int nblk)
{
    __shared__ u16 As[128][64];
    __shared__ u16 Bs[128][64];
    const int flat = blockIdx.x;
    const int nper = gridDim.x >> 3;
    const int r    = (flat & 7) * nper + (flat >> 3);
    const int z    = r / nblk;
    const int bi   = r - z * nblk;
    const int by   = bi / nbx;
    const int bx   = bi - by * nbx;

    const int row0 = by * 128;
    const int col0 = bx * 128;
    const int t    = threadIdx.x;
    const int lane = t & 63;
    const int wave = t >> 6;
    const int wr   = (wave >> 1) * 64;
    const int wc   = (wave & 1) * 64;

    const int srow  = t >> 1;
    const int shalf = t & 1;
    const int agrow = row0 + srow;
    const long aRowOff = (long)z * aZ + (long)(agrow >> 6) * rgsA
                       + (long)(agrow & 63) * lda;
    const long bRowOff = (long)z * bZ + (long)(col0 + srow) * ldb;

    f32x4 acc[4][4] = {};

    for (int k0 = 0; k0 < K; k0 += 64) {
        if (AF32) {
            const float* pa = (const float*)Av + aRowOff + k0 + shalf * 32;
            #pragma unroll
            for (int q = 0; q < 4; ++q) {
                float4 u0 = *(const float4*)(pa + q * 8);
                float4 u1 = *(const float4*)(pa + q * 8 + 4);
                u16 tmp[8] = { f2b(u0.x), f2b(u0.y), f2b(u0.z), f2b(u0.w),
                               f2b(u1.x), f2b(u1.y), f2b(u1.z), f2b(u1.w) };
                const int cs = (shalf * 4 + q) ^ (srow & 7);
                *(uint4*)&As[srow][cs * 8] = *(const uint4*)tmp;
            }
        } else {
            const u16* pa = (const u16*)Av + aRowOff + k0 + shalf * 32;
            #pragma unroll
            for (int q = 0; q < 4; ++q) {
                uint4 v = *(const uint4*)(pa + q * 8);
                const int cs = (shalf * 4 + q) ^ (srow & 7);
                *(uint4*)&As[srow][cs * 8] = v;
            }
        }
        {
            const u16* pb = Bt + bRowOff + k0 + shalf * 32;
            #pragma unroll
            for (int q = 0; q < 4; ++q) {
                uint4 v = *(const uint4*)(pb + q * 8);
                const int cs = (shalf * 4 + q) ^ (srow & 7);
                *(uint4*)&Bs[srow][cs * 8] = v;
            }
        }
        __syncthreads();

        #pragma unroll
        for (int kk = 0; kk < 2; ++kk) {
            const int cchunk = kk * 4 + (lane >> 4);
            bf16x8 af[4], bfr[4];
            #pragma unroll
            for (int i = 0; i < 4; ++i) {
                const int m = wr + i * 16 + (lane & 15);
                af[i]  = __builtin_bit_cast(bf16x8,
                           *(const uint4*)&As[m][(cchunk ^ (m & 7)) * 8]);
                const int n = wc + i * 16 + (lane & 15);
                bfr[i] = __builtin_bit_cast(bf16x8,
                           *(const uint4*)&Bs[n][(cchunk ^ (n & 7)) * 8]);
            }
            #pragma unroll
            for (int i = 0; i < 4; ++i)
                #pragma unroll
                for (int j = 0; j < 4; ++j)
                    acc[i][j] = __builtin_amdgcn_mfma_f32_16x16x32_bf16(
                                    af[i], bfr[j], acc[i][j], 0, 0, 0);
        }
        __syncthreads();
    }

    const int cq = lane >> 4;
    #pragma unroll
    for (int j = 0; j < 4; ++j) {
        const int gcol = col0 + wc + j * 16 + (lane & 15);
        const float bv = bias ? bias[(long)z * biasZ + gcol] : 0.f;
        #pragma unroll
        for (int i = 0; i < 4; ++i) {
            #pragma unroll
            for (int r2 = 0; r2 < 4; ++r2) {
                const int grow = row0 + wr + i * 16 + cq * 4 + r2;
                const long co = (long)z * cZ + (long)(grow >> 6) * rgsC
                              + (long)(grow & 63) * ldc + gcol;
                float v = acc[i][j][r2] + bv;
                if (DOGELU) v = gelu_f(v);
                if (CF32) ((float*)Cv)[co] = v;
                else      ((u16*)Cv)[co]  = f2b(v);
                if (Cb2)  Cb2[co] = f2b(v);
            }
        }
    }
}

// ---------------------------------------------------------------------------
// Transpose [z][R][C] (fp32 or bf16) -> [z][C][R] bf16. 64x64 tiles, 256 thr.
template<bool F32>
__global__ __launch_bounds__(256)
void transpose_k(const void* __restrict__ inV, u16* __restrict__ out, int R, int C)
{
    __shared__ u16 tile[64][72];
    const long zin = (long)blockIdx.z * R * C;
    const int r0 = blockIdx.y * 64, c0 = blockIdx.x * 64;
    const int t  = threadIdx.x;
    const int tr = t >> 4;
    const int tc = (t & 15) * 4;
    #pragma unroll
    for (int p = 0; p < 4; ++p) {
        const int r = tr + p * 16;
        if (F32) {
            float4 v = *(const float4*)((const float*)inV + zin + (long)(r0 + r) * C + c0 + tc);
            tile[r][tc+0] = f2b(v.x); tile[r][tc+1] = f2b(v.y);
            tile[r][tc+2] = f2b(v.z); tile[r][tc+3] = f2b(v.w);
        } else {
            ushort4 v = *(const ushort4*)((const u16*)inV + zin + (long)(r0 + r) * C + c0 + tc);
            tile[r][tc+0] = v.x; tile[r][tc+1] = v.y;
            tile[r][tc+2] = v.z; tile[r][tc+3] = v.w;
        }
    }
    __syncthreads();
    #pragma unroll
    for (int p = 0; p < 4; ++p) {
        const int rr = tr + p * 16;
        ushort4 o;
        o.x = tile[tc+0][rr]; o.y = tile[tc+1][rr];
        o.z = tile[tc+2][rr]; o.w = tile[tc+3][rr];
        *(ushort4*)(out + (long)blockIdx.z * R * C + (long)(c0 + rr) * R + r0 + tc) = o;
    }
}

// ---------------------------------------------------------------------------
// dispatch softmax over m, in place (fallback path)
__global__ __launch_bounds__(1024)
void softmax_m(float* __restrict__ logits)
{
    const int b   = blockIdx.y;
    const int c   = threadIdx.x & 15;
    const int col = blockIdx.x * 16 + c;
    const int mg  = threadIdx.x >> 4;
    float* base = logits + (long)b * 1048576 + col;

    float vals[16];
    float mx = -3.4e38f;
    #pragma unroll
    for (int i = 0; i < 16; ++i) {
        float v = base[(long)(mg * 16 + i) * 1024];
        vals[i] = v;
        mx = fmaxf(mx, v);
    }
    __shared__ float red[64][16];
    red[mg][c] = mx;
    __syncthreads();
    for (int s = 32; s >= 1; s >>= 1) {
        if (mg < s) red[mg][c] = fmaxf(red[mg][c], red[mg + s][c]);
        __syncthreads();
    }
    mx = red[0][c];
    __syncthreads();
    float ssum = 0.f;
    #pragma unroll
    for (int i = 0; i < 16; ++i) { vals[i] = expf(vals[i] - mx); ssum += vals[i]; }
    red[mg][c] = ssum;
    __syncthreads();
    for (int s = 32; s >= 1; s >>= 1) {
        if (mg < s) red[mg][c] += red[mg + s][c];
        __syncthreads();
    }
    const float inv = 1.f / red[0][c];
    #pragma unroll
    for (int i = 0; i < 16; ++i)
        base[(long)(mg * 16 + i) * 1024] = vals[i] * inv;
}

// dispatch softmax over m -> dispT[b][ep][m] bf16 (MFMA path; logits untouched)
__global__ __launch_bounds__(1024)
void softmax_mT(const float* __restrict__ logits, u16* __restrict__ dispT)
{
    const int b   = blockIdx.y;
    const int c   = threadIdx.x & 15;
    const int col = blockIdx.x * 16 + c;
    const int mg  = threadIdx.x >> 4;
    const float* base = logits + (long)b * 1048576 + col;

    float vals[16];
    float mx = -3.4e38f;
    #pragma unroll
    for (int i = 0; i < 16; ++i) {
        float v = base[(long)(mg * 16 + i) * 1024];
        vals[i] = v;
        mx = fmaxf(mx, v);
    }
    __shared__ float red[64][16];
    red[mg][c] = mx;
    __syncthreads();
    for (int s = 32; s >= 1; s >>= 1) {
        if (mg < s) red[mg][c] = fmaxf(red[mg][c], red[mg + s][c]);
        __syncthreads();
    }
    mx = red[0][c];
    __syncthreads();
    float ssum = 0.f;
    #pragma unroll
    for (int i = 0; i < 16; ++i) { vals[i] = expf(vals[i] - mx); ssum += vals[i]; }
    red[mg][c] = ssum;
    __syncthreads();
    for (int s = 32; s >= 1; s >>= 1) {
        if (mg < s) red[mg][c] += red[mg + s][c];
        __syncthreads();
    }
    const float inv = 1.f / red[0][c];

    union { u16 s[16]; uint4 q[2]; } pk;
    #pragma unroll
    for (int i = 0; i < 16; ++i) pk.s[i] = f2b(vals[i] * inv);
    u16* ob = dispT + (long)b * 1048576 + (long)col * 1024 + mg * 16;
    *(uint4*)ob       = pk.q[0];
    *(uint4*)(ob + 8) = pk.q[1];
}

// combine softmax over (e,p), + probabilities (fp32-exact) + argmax (fp32-exact)
template<bool B16>
__global__ __launch_bounds__(256)
void softmax_ep(const float* __restrict__ logits, void* __restrict__ comb,
                float* __restrict__ probs, float* __restrict__ tops)
{
    const long r = blockIdx.x;
    const int  t = threadIdx.x;
    const float* row = logits + r * 1024;
    float4 v = *(const float4*)(row + t * 4);

    float mx = fmaxf(fmaxf(v.x, v.y), fmaxf(v.z, v.w));
    #pragma unroll
    for (int s = 32; s; s >>= 1) mx = fmaxf(mx, __shfl_xor(mx, s));
    __shared__ float wr_[4];
    const int wid = t >> 6;
    if ((t & 63) == 0) wr_[wid] = mx;
    __syncthreads();
    mx = fmaxf(fmaxf(wr_[0], wr_[1]), fmaxf(wr_[2], wr_[3]));
    __syncthreads();

    float e0 = expf(v.x - mx), e1 = expf(v.y - mx);
    float e2 = expf(v.z - mx), e3 = expf(v.w - mx);
    float s4 = e0 + e1 + e2 + e3;
    float sm = s4;
    #pragma unroll
    for (int s = 32; s; s >>= 1) sm += __shfl_xor(sm, s);
    if ((t & 63) == 0) wr_[wid] = sm;
    __syncthreads();
    const float tot = wr_[0] + wr_[1] + wr_[2] + wr_[3];
    const float inv = 1.f / tot;

    if (B16) {
        ushort4 o;
        o.x = f2b(e0 * inv); o.y = f2b(e1 * inv);
        o.z = f2b(e2 * inv); o.w = f2b(e3 * inv);
        *(ushort4*)((u16*)comb + r * 1024 + t * 4) = o;
    } else {
        float4 o = make_float4(e0 * inv, e1 * inv, e2 * inv, e3 * inv);
        *(float4*)((float*)comb + r * 1024 + t * 4) = o;
    }

    __shared__ float es[16][16];
    es[t >> 4][t & 15] = s4 * inv;
    __syncthreads();
    __shared__ float pr[16];
    if (t < 16) {
        float ss = 0.f;
        #pragma unroll
        for (int i = 0; i < 16; ++i) ss += es[t][i];
        float p = ss * (1.f / 64.f);
        probs[r * 16 + t] = p;
        pr[t] = p;
    }
    __syncthreads();
    if (t == 0) {
        int best = 0; float bv = pr[0];
        #pragma unroll
        for (int e = 1; e < 16; ++e)
            if (pr[e] > bv) { bv = pr[e]; best = e; }
        tops[r] = (float)best;
    }
}

// ---------------------------------------------------------------------------
extern "C" void kernel_launch(void* const* d_in, const int* in_sizes, int n_in,
                              void* d_out, int out_size, void* d_ws, size_t ws_size,
                              hipStream_t stream)
{
    (void)in_sizes; (void)n_in; (void)out_size;
    const float* x   = (const float*)d_in[0];
    const float* phi = (const float*)d_in[1];
    const float* W1  = (const float*)d_in[2];
    const float* b1  = (const float*)d_in[3];
    const float* W2  = (const float*)d_in[4];
    const float* b2  = (const float*)d_in[5];

    float* outputs = (float*)d_out;
    float* probs   = outputs + 3145728;
    float* tops    = outputs + 3145728 + 65536;
    float* hid     = outputs + 3145728 + 65536 + 4096;   // [4][16][64][3072] fp32

    char* wsb = (char*)d_ws;

    if (ws_size >= 209715200ull) {
        // ================= MFMA path (needs 200 MiB ws) =================
        float* logits = (float*)(wsb);                    // 16 MiB (dead after K2)
        u16*   combB  = (u16*)(wsb + 16777216);           // 8 MiB
        u16*   dispT  = (u16*)(wsb + 25165824);           // 8 MiB
        u16*   xT     = (u16*)(wsb + 33554432);           // 6 MiB
        u16*   mixB   = (u16*)(wsb + 39845888);           // 6 MiB
        u16*   W1T    = (u16*)(wsb + 46137344);           // 72 MiB
        u16*   W2T    = (u16*)(wsb + 121634816);          // 72 MiB
        u16*   eoutN  = (u16*)(wsb + 197132288);          // 6 MiB
        u16*   eoutT  = (u16*)(wsb + 203423744);          // 6 MiB
        u16*   hidB   = (u16*)wsb;                        // 12.6 MiB, aliases dead logits

        // T1-T3: W1 -> W1T[e][f][d], W2 -> W2T[e][d][f], x -> xT[b][d][m]
        transpose_k<true><<<dim3(48, 12, 16), 256, 0, stream>>>(W1, W1T, 768, 3072);
        transpose_k<true><<<dim3(12, 48, 16), 256, 0, stream>>>(W2, W2T, 3072, 768);
        transpose_k<true><<<dim3(12, 16, 4),  256, 0, stream>>>(x,  xT,  1024, 768);

        // K1: logits = x @ phi (fp32 — keeps probabilities/argmax exact)
        gemm_logits<<<dim3(8, 32), 512, 0, stream>>>(x, phi, logits);

        // K2: combine softmax (bf16 comb + fp32 probs/tops); dispatch softmax -> dispT
        softmax_ep<true><<<dim3(4096), 256, 0, stream>>>(logits, combB, probs, tops);
        softmax_mT<<<dim3(64, 4), 1024, 0, stream>>>(logits, dispT);

        // K3: mix[b][ep][d] = dispT[b] @ x[b]  (M=1024,N=768,K=1024), z=b
        mfma_gemm<false, false, false><<<dim3(192), 256, 0, stream>>>(
            dispT, xT, nullptr, mixB, nullptr,
            1024, 1024, 1024, 768, 1048576L, 786432L, 786432L, 0,
            65536L, 49152L, 6, 48);

        // K4: hidden = gelu(mix @ W1 + b1) -> d_out fp32 + hidB bf16 (dual store)
        mfma_gemm<false, true, true><<<dim3(768), 256, 0, stream>>>(
            mixB, W1T, b1, hid, hidB,
            768, 768, 768, 3072, 49152L, 2359296L, 196608L, 3072,
            786432L, 3145728L, 24, 48);

        // K5: eout = hidB @ W2 + b2 (A=bf16; M=256,N=768,K=3072, z=e)
        mfma_gemm<false, false, false><<<dim3(192), 256, 0, stream>>>(
            hidB, W2T, b2, eoutN, nullptr,
            3072, 3072, 3072, 768, 196608L, 2359296L, 49152L, 768,
            3145728L, 786432L, 6, 12);

        // T4: eoutN[b][ep][d] -> eoutT[b][d][ep]
        transpose_k<false><<<dim3(12, 16, 4), 256, 0, stream>>>(eoutN, eoutT, 1024, 768);

        // K6: outputs[b] = combB[b] @ eoutT[b]  (M=1024,N=768,K=1024), z=b
        mfma_gemm<false, false, true><<<dim3(192), 256, 0, stream>>>(
            combB, eoutT, nullptr, outputs, nullptr,
            1024, 1024, 1024, 768, 1048576L, 786432L, 786432L, 0,
            65536L, 49152L, 6, 48);
    } else {
        // ================= fallback: round-1 fp32 path (44 MiB ws) =================
        float* logits = (float*)wsb;                  // becomes disp in place
        float* comb   = (float*)(wsb + 16777216);
        float* mixb   = (float*)(wsb + 33554432);
        float* eout   = (float*)wsb;                  // aliases dead disp

        gemm_k<false, false><<<dim3(16, 32, 1), 256, 0, stream>>>(
            x, phi, nullptr, logits,
            768, 768, 1024, 1024, 0L, 0L, 0L, 0, 64L * 768, 64L * 1024);
        softmax_ep<false><<<dim3(4096), 256, 0, stream>>>(logits, comb, probs, tops);
        softmax_m<<<dim3(64, 4), 1024, 0, stream>>>(logits);
        gemm_k<true, false><<<dim3(12, 8, 4), 256, 0, stream>>>(
            logits, x, nullptr, mixb,
            1024, 1024, 768, 768, 1048576L, 786432L, 786432L, 0, 0L, 64L * 768);
        gemm_k<false, true><<<dim3(48, 2, 16), 256, 0, stream>>>(
            mixb, W1, b1, hid,
            768, 768, 3072, 3072, 49152L, 2359296L, 196608L, 3072,
            786432L, 3145728L);
        gemm_k<false, false><<<dim3(12, 2, 16), 256, 0, stream>>>(
            hid, W2, b2, eout,
            3072, 3072, 768, 768, 196608L, 2359296L, 49152L, 768,
            3145728L, 786432L);
        gemm_k<false, false><<<dim3(12, 8, 4), 256, 0, stream>>>(
            comb, eout, nullptr, outputs,
            1024, 1024, 768, 768, 1048576L, 786432L, 786432L, 0,
            64L * 1024, 64L * 768);
    }
}